// Round 20
// baseline (125.278 us; speedup 1.0000x reference)
//
#include <hip/hip_runtime.h>
#include <stdint.h>

#define IN_F 4096
#define OUT_F 4096
#define M_ROWS 4096   // B*S
#define BM 128
#define BN 128
#define BK 32
#define ABUF_B (BM * BK * 2)       // 8 KiB
#define BBUF_B (BN * BK * 2)       // 8 KiB
#define BUF_B (ABUF_B + BBUF_B)    // 16 KiB per depth

typedef __attribute__((ext_vector_type(8))) short bf16x8;
typedef __attribute__((ext_vector_type(4))) float f32x4;
typedef __attribute__((ext_vector_type(4))) float f4;
typedef __attribute__((ext_vector_type(8))) unsigned short u16x8;

__device__ __forceinline__ unsigned short f32_to_bf16_rne(float f) {
    uint32_t u = __float_as_uint(f);
    u += 0x7FFFu + ((u >> 16) & 1u);
    return (unsigned short)(u >> 16);
}

// ---- merged prepass, grid-strided (2048 blocks x 8 virtual) ----
__global__ __launch_bounds__(256) void prep_kernel(const float* __restrict__ x,
                                                   const float* __restrict__ wsrc,
                                                   unsigned short* __restrict__ xb,
                                                   unsigned short* __restrict__ wb) {
#pragma unroll
    for (int it = 0; it < 8; ++it) {
        int vb = blockIdx.x + it * 2048;
        if (vb < 8192) {
            size_t g = (size_t)vb * 256 + threadIdx.x;   // one per 8 elems
            const f4* xp = (const f4*)x + g * 2;
            f4 a = xp[0], c = xp[1];
            u16x8 r;
            r[0] = f32_to_bf16_rne(a[0]); r[1] = f32_to_bf16_rne(a[1]);
            r[2] = f32_to_bf16_rne(a[2]); r[3] = f32_to_bf16_rne(a[3]);
            r[4] = f32_to_bf16_rne(c[0]); r[5] = f32_to_bf16_rne(c[1]);
            r[6] = f32_to_bf16_rne(c[2]); r[7] = f32_to_bf16_rne(c[3]);
            *((u16x8*)xb + g) = r;
        } else {
            size_t g = (size_t)(vb - 8192) * 256 + threadIdx.x;
            int o  = (int)(g >> 9);
            int i0 = ((int)g & 511) << 3;
            int bs = (o >> 7) << 7;        // GEMM never reads k < 128-aligned n_base
            if (i0 >= bs) {
                int off = o * IN_F - ((o * (o - 1)) >> 1);
                u16x8 r;
#pragma unroll
                for (int j = 0; j < 8; ++j) {
                    int i = i0 + j;
                    float v = (i >= o) ? wsrc[off + (i - o)] : 0.0f;
                    r[j] = f32_to_bf16_rne(v);
                }
                *((u16x8*)wb + g) = r;
            }
        }
    }
}

// ---- LDS layout: R5/R17-verified pair-line XOR swizzle (BK=32 rows, conflict-free) ----
// row = 32 bf16 = 64B = 4 slots of 16B; two rows share a 128B line.
// byte(row, slot) = (row>>1)*128 + (((row&1)*4 + slot) ^ ((row>>1)&7)) * 16
__device__ __forceinline__ const bf16x8* lds_frag(const char* buf, int row, int khalf) {
    const int line = row >> 1;
    const int pos  = ((((row & 1) << 2) + khalf) ^ (line & 7));
    return (const bf16x8*)(buf + line * 128 + pos * 16);
}

// stage one 16-row unit (1 KiB) via global_load_lds; dest linear, source pre-swizzled
__device__ __forceinline__ void stage16(const unsigned short* __restrict__ G,
                                        char* lds_dst, int gr0, int k0, int lane) {
    const int pos  = (lane & 7) ^ (lane >> 3);
    const int row  = ((lane >> 3) << 1) + (pos >> 2);
    const int slot = pos & 3;
    const unsigned short* src = G + (size_t)(gr0 + row) * IN_F + k0 + slot * 8;
    __builtin_amdgcn_global_load_lds(
        (const __attribute__((address_space(1))) void*)src,
        (__attribute__((address_space(3))) void*)lds_dst, 16, 0, 0);
}

// one K32-tile: A 128x32 (8 units) + B 128x32 (8 units), 4 waves -> 4 issues/thread
__device__ __forceinline__ void stage_tile(const unsigned short* __restrict__ A,
                                           const unsigned short* __restrict__ W,
                                           char* buf, int m_base, int n_base, int k0,
                                           int wid, int lane) {
    char* bufA = buf;
    char* bufB = buf + ABUF_B;
#pragma unroll
    for (int q = 0; q < 2; ++q) {
        const int un = wid * 2 + q;                 // 0..7
        stage16(A, bufA + un * 1024, m_base + un * 16, k0, lane);
        stage16(W, bufB + un * 1024, n_base + un * 16, k0, lane);
    }
}

// ---- main GEMM: C[m][n] = sum_{k>=n_base} A[m][k]*W[n][k] + bias[n] ----
// 128x128 tile, BK=32, 4 waves (2x2, wave 64x64), depth-3 LDS = 48 KB -> 3 blocks/CU.
// R2's one-barrier depth-3 loop + R15's counted-vmcnt discipline + 1024-job refill grid.
// Lever vs R15: 3-way inter-block TLP (12 waves/CU) with halved per-tile barrier count.
__global__ __launch_bounds__(256, 3) void tri_gemm_kernel(const unsigned short* __restrict__ A,
                                                          const unsigned short* __restrict__ W,
                                                          const float* __restrict__ bias,
                                                          float* __restrict__ C) {
    __shared__ __align__(16) char smem[3 * BUF_B];   // 48 KiB triple buffer

    const int u = blockIdx.x;
    const int tile_n = u >> 5;          // desc-K dispatch -> greedy LPT via refill
    const int tile_m = u & 31;
    const int m_base = tile_m * BM;
    const int n_base = tile_n * BN;
    const int nt = (IN_F - n_base) / BK;   // 128 - 4*tile_n, min 4

    const int tid  = threadIdx.x;
    const int wid  = tid >> 6;
    const int lane = tid & 63;
    const int wr = wid >> 1;            // 0..1 (64-row band)
    const int wc = wid & 1;             // 0..1 (64-col band)
    const int frow  = lane & 15;
    const int khalf = lane >> 4;        // 0..3 (16B k-slot of the K32 row)

    char* b0 = smem;
    char* b1 = smem + BUF_B;
    char* b2 = smem + 2 * BUF_B;

    f32x4 acc[4][4];
#pragma unroll
    for (int i = 0; i < 4; ++i)
#pragma unroll
        for (int j = 0; j < 4; ++j) acc[i][j] = (f32x4){0.f, 0.f, 0.f, 0.f};

    // prologue: tiles 0,1 staged (4 loads each per thread -> 8 outstanding)
    stage_tile(A, W, b0, m_base, n_base, n_base,      wid, lane);
    stage_tile(A, W, b1, m_base, n_base, n_base + BK, wid, lane);

    for (int t = 0; t < nt; ++t) {
        // publish tile t; tile t+1's 4 loads stay in flight (never drain mid-loop)
        if (t + 1 < nt) { asm volatile("s_waitcnt vmcnt(4)" ::: "memory"); }
        else            { asm volatile("s_waitcnt vmcnt(0)" ::: "memory"); }
        __builtin_amdgcn_sched_barrier(0);
        __builtin_amdgcn_s_barrier();   // also closes WAR on b2: all waves' t-1 reads retired
        __builtin_amdgcn_sched_barrier(0);

        if (t + 2 < nt)                 // prefetch t+2 into buffer freed by t-1
            stage_tile(A, W, b2, m_base, n_base, n_base + (t + 2) * BK, wid, lane);

        const char* bufA = b0;
        const char* bufB = b0 + ABUF_B;

        bf16x8 af[4], bfr[4];
#pragma unroll
        for (int mi = 0; mi < 4; ++mi)
            af[mi] = *lds_frag(bufA, wr * 64 + mi * 16 + frow, khalf);
#pragma unroll
        for (int nj = 0; nj < 4; ++nj)
            bfr[nj] = *lds_frag(bufB, wc * 64 + nj * 16 + frow, khalf);
        __builtin_amdgcn_s_setprio(1);
#pragma unroll
        for (int mi = 0; mi < 4; ++mi)
#pragma unroll
            for (int nj = 0; nj < 4; ++nj)
                acc[mi][nj] = __builtin_amdgcn_mfma_f32_16x16x32_bf16(af[mi], bfr[nj], acc[mi][nj], 0, 0, 0);
        __builtin_amdgcn_s_setprio(0);

        asm volatile("s_waitcnt lgkmcnt(0)" ::: "memory");   // this wave's reads retired
        __builtin_amdgcn_sched_barrier(0);

        char* tmp = b0; b0 = b1; b1 = b2; b2 = tmp;          // rotate
    }

    // ---- epilogue: D layout col=lane&15, row=(lane>>4)*4+q ----
    const int col0 = n_base + wc * 64;
    const int row0 = m_base + wr * 64;
#pragma unroll
    for (int nj = 0; nj < 4; ++nj) {
        const int col = col0 + nj * 16 + frow;
        const float bv = bias[col];
#pragma unroll
        for (int mi = 0; mi < 4; ++mi) {
            const int rbase = row0 + mi * 16 + khalf * 4;
#pragma unroll
            for (int q = 0; q < 4; ++q) {
                C[(size_t)(rbase + q) * OUT_F + col] = acc[mi][nj][q] + bv;
            }
        }
    }
}

extern "C" void kernel_launch(void* const* d_in, const int* in_sizes, int n_in,
                              void* d_out, int out_size, void* d_ws, size_t ws_size,
                              hipStream_t stream) {
    const float* x    = (const float*)d_in[0];
    const float* w    = (const float*)d_in[1];
    const float* bias = (const float*)d_in[2];
    float* out = (float*)d_out;

    unsigned short* xb = (unsigned short*)d_ws;                  // 32 MiB bf16 x
    unsigned short* wb = xb + (size_t)M_ROWS * IN_F;             // 32 MiB bf16 dense W

    prep_kernel<<<2048, 256, 0, stream>>>(x, w, xb, wb);
    tri_gemm_kernel<<<1024, 256, 0, stream>>>(xb, wb, bias, out);
}

// Round 21
// 103.735 us; speedup vs baseline: 1.2077x; 1.2077x over previous
//
#include <hip/hip_runtime.h>
#include <stdint.h>

#define IN_F 4096
#define OUT_F 4096
#define M_ROWS 4096   // B*S
#define BM 128
#define BN 128
#define BK 64
#define ABUF_B (BM * BK * 2)       // 16 KiB
#define BBUF_B (BN * BK * 2)       // 16 KiB
#define BUF_B (ABUF_B + BBUF_B)    // 32 KiB per depth

typedef __attribute__((ext_vector_type(8))) short bf16x8;
typedef __attribute__((ext_vector_type(4))) float f32x4;
typedef __attribute__((ext_vector_type(4))) float f4;
typedef __attribute__((ext_vector_type(8))) unsigned short u16x8;

__device__ __forceinline__ unsigned short f32_to_bf16_rne(float f) {
    uint32_t u = __float_as_uint(f);
    u += 0x7FFFu + ((u >> 16) & 1u);
    return (unsigned short)(u >> 16);
}

// ---- merged prepass, grid-strided (2048 blocks x 8 virtual): ----
// vb in [0,8192): x fp32->bf16 ; vb in [8192,16384): W triangle expand
__global__ __launch_bounds__(256) void prep_kernel(const float* __restrict__ x,
                                                   const float* __restrict__ wsrc,
                                                   unsigned short* __restrict__ xb,
                                                   unsigned short* __restrict__ wb) {
#pragma unroll
    for (int it = 0; it < 8; ++it) {
        int vb = blockIdx.x + it * 2048;
        if (vb < 8192) {
            size_t g = (size_t)vb * 256 + threadIdx.x;   // one per 8 elems
            const f4* xp = (const f4*)x + g * 2;
            f4 a = xp[0], c = xp[1];
            u16x8 r;
            r[0] = f32_to_bf16_rne(a[0]); r[1] = f32_to_bf16_rne(a[1]);
            r[2] = f32_to_bf16_rne(a[2]); r[3] = f32_to_bf16_rne(a[3]);
            r[4] = f32_to_bf16_rne(c[0]); r[5] = f32_to_bf16_rne(c[1]);
            r[6] = f32_to_bf16_rne(c[2]); r[7] = f32_to_bf16_rne(c[3]);
            *((u16x8*)xb + g) = r;
        } else {
            size_t g = (size_t)(vb - 8192) * 256 + threadIdx.x;
            int o  = (int)(g >> 9);
            int i0 = ((int)g & 511) << 3;
            int bs = (o >> 7) << 7;        // GEMM never reads i < 128-aligned block start
            if (i0 >= bs) {
                int off = o * IN_F - ((o * (o - 1)) >> 1);
                u16x8 r;
#pragma unroll
                for (int j = 0; j < 8; ++j) {
                    int i = i0 + j;
                    float v = (i >= o) ? wsrc[off + (i - o)] : 0.0f;
                    r[j] = f32_to_bf16_rne(v);
                }
                *((u16x8*)wb + g) = r;
            }
        }
    }
}

// ---- staging: 8-row x 128B unit via global_load_lds; dest linear, source pre-swizzled ----
// LDS row layout: [row][8 slots x 16B], byte(row,slot) = row*128 + (slot ^ (row&7))*16
__device__ __forceinline__ void stage16(const unsigned short* __restrict__ G,
                                        char* lds_dst, int gr0, int k0, int lane) {
    const int lrow  = lane >> 3;                 // 0..7
    const int gslot = (lane & 7) ^ lrow;         // pre-swizzled source slot
    const unsigned short* src = G + (size_t)(gr0 + lrow) * IN_F + k0 + gslot * 8;
    __builtin_amdgcn_global_load_lds(
        (const __attribute__((address_space(1))) void*)src,
        (__attribute__((address_space(3))) void*)lds_dst, 16, 0, 0);
}

// one K64-tile: A 128x64 + B 128x64, 4 waves -> 8 gload_lds per thread
__device__ __forceinline__ void stage_tile(const unsigned short* __restrict__ A,
                                           const unsigned short* __restrict__ W,
                                           char* buf, int m_base, int n_base, int k0,
                                           int wid, int lane) {
    char* bufA = buf;
    char* bufB = buf + ABUF_B;
#pragma unroll
    for (int q = 0; q < 4; ++q) {                // A: 32 rows per wave
        const int r0 = q * 32 + wid * 8;
        stage16(A, bufA + r0 * 128, m_base + r0, k0, lane);
    }
#pragma unroll
    for (int q = 0; q < 4; ++q) {                // B: 32 rows per wave
        const int r0 = q * 32 + wid * 8;
        stage16(W, bufB + r0 * 128, n_base + r0, k0, lane);
    }
}

__device__ __forceinline__ const bf16x8* lds_frag(const char* buf, int row, int slot) {
    return (const bf16x8*)(buf + row * 128 + ((slot ^ (row & 7)) * 16));
}

// ---- main GEMM: C[m][n] = sum_{k>=n_base} A[m][k]*W[n][k] + bias[n] ----
// R15 champion, verbatim: 128x128 tile, 4 waves (2x2, wave 64x64), depth-2 LDS = 64 KB
// -> 2 blocks/CU; 1024 desc-K jobs for refill balance; counted vmcnt; 2 barriers/tile.
__global__ __launch_bounds__(256, 2) void tri_gemm_kernel(const unsigned short* __restrict__ A,
                                                          const unsigned short* __restrict__ W,
                                                          const float* __restrict__ bias,
                                                          float* __restrict__ C) {
    __shared__ __align__(16) char smem[2 * BUF_B];   // 64 KiB double buffer

    const int u = blockIdx.x;
    const int tile_n = u >> 5;          // desc-K dispatch -> greedy LPT via refill
    const int tile_m = u & 31;
    const int m_base = tile_m * BM;
    const int n_base = tile_n * BN;
    const int nt = (IN_F - n_base) / BK;   // 64 - 2*tile_n, even, min 2

    const int tid  = threadIdx.x;
    const int wid  = tid >> 6;
    const int lane = tid & 63;
    const int wr = wid >> 1;            // 0..1 (64-row band)
    const int wc = wid & 1;             // 0..1 (64-col band)
    const int frow  = lane & 15;
    const int khalf = lane >> 4;

    char* buf0 = smem;
    char* buf1 = smem + BUF_B;

    f32x4 acc[4][4];
#pragma unroll
    for (int i = 0; i < 4; ++i)
#pragma unroll
        for (int j = 0; j < 4; ++j) acc[i][j] = (f32x4){0.f, 0.f, 0.f, 0.f};

    // prologue: tiles 0,1 staged (8 loads each per thread -> 16 outstanding)
    stage_tile(A, W, buf0, m_base, n_base, n_base,      wid, lane);
    stage_tile(A, W, buf1, m_base, n_base, n_base + BK, wid, lane);

    for (int t = 0; t < nt; ++t) {
        // publish tile t: keep tile t+1's 8 loads in flight (never drain mid-loop)
        if (t + 1 < nt) { asm volatile("s_waitcnt vmcnt(8)" ::: "memory"); }
        else            { asm volatile("s_waitcnt vmcnt(0)" ::: "memory"); }
        __builtin_amdgcn_sched_barrier(0);
        __builtin_amdgcn_s_barrier();
        __builtin_amdgcn_sched_barrier(0);

        const char* cur  = (t & 1) ? buf1 : buf0;
        const char* bufA = cur;
        const char* bufB = cur + ABUF_B;

        bf16x8 af[2][4], bfr[2][4];
#pragma unroll
        for (int kh = 0; kh < 2; ++kh) {
            const int slot = kh * 4 + khalf;
#pragma unroll
            for (int mi = 0; mi < 4; ++mi)
                af[kh][mi] = *lds_frag(bufA, wr * 64 + mi * 16 + frow, slot);
#pragma unroll
            for (int nj = 0; nj < 4; ++nj)
                bfr[kh][nj] = *lds_frag(bufB, wc * 64 + nj * 16 + frow, slot);
        }
        __builtin_amdgcn_s_setprio(1);
#pragma unroll
        for (int kh = 0; kh < 2; ++kh)
#pragma unroll
            for (int mi = 0; mi < 4; ++mi)
#pragma unroll
                for (int nj = 0; nj < 4; ++nj)
                    acc[mi][nj] = __builtin_amdgcn_mfma_f32_16x16x32_bf16(af[kh][mi], bfr[kh][nj], acc[mi][nj], 0, 0, 0);
        __builtin_amdgcn_s_setprio(0);

        // WAR close: all waves' reads of buf[t&1] retired before restaging it
        asm volatile("s_waitcnt lgkmcnt(0)" ::: "memory");
        __builtin_amdgcn_sched_barrier(0);
        __builtin_amdgcn_s_barrier();
        __builtin_amdgcn_sched_barrier(0);

        if (t + 2 < nt)
            stage_tile(A, W, (t & 1) ? buf1 : buf0, m_base, n_base,
                       n_base + (t + 2) * BK, wid, lane);
    }

    // ---- epilogue: D layout col=lane&15, row=(lane>>4)*4+q ----
    const int col0 = n_base + wc * 64;
    const int row0 = m_base + wr * 64;
#pragma unroll
    for (int nj = 0; nj < 4; ++nj) {
        const int col = col0 + nj * 16 + frow;
        const float bv = bias[col];
#pragma unroll
        for (int mi = 0; mi < 4; ++mi) {
            const int rbase = row0 + mi * 16 + khalf * 4;
#pragma unroll
            for (int q = 0; q < 4; ++q) {
                C[(size_t)(rbase + q) * OUT_F + col] = acc[mi][nj][q] + bv;
            }
        }
    }
}

extern "C" void kernel_launch(void* const* d_in, const int* in_sizes, int n_in,
                              void* d_out, int out_size, void* d_ws, size_t ws_size,
                              hipStream_t stream) {
    const float* x    = (const float*)d_in[0];
    const float* w    = (const float*)d_in[1];
    const float* bias = (const float*)d_in[2];
    float* out = (float*)d_out;

    unsigned short* xb = (unsigned short*)d_ws;                  // 32 MiB bf16 x
    unsigned short* wb = xb + (size_t)M_ROWS * IN_F;             // 32 MiB bf16 dense W

    prep_kernel<<<2048, 256, 0, stream>>>(x, w, xb, wb);
    tri_gemm_kernel<<<1024, 256, 0, stream>>>(xb, wb, bias, out);
}